// Round 9
// baseline (613.270 us; speedup 1.0000x reference)
//
#include <hip/hip_runtime.h>
#include <stdint.h>

// TensorProductConvLayer — round 9: phase-split LDS staging in edge kernel.
//
// R8 post-mortem: edge_mfma 185us, MfmaUtil 15.5%, VALUBusy 11%, Occupancy
// 19% <- LDS 56,832B caps at 2 blocks/CU (2 waves/SIMD): bpk L2 loads
// (~200cy) can't be hidden. Fix: xs+dt (24,576B, phases A+B) and xv
// (24,576B, phase C) time-share ONE union buffer; LDS -> 32,000B ->
// 4 blocks/CU = 16 waves/CU. Extra cost: 2 barriers + L2-hit na re-read.
//
// Precision: A and B split h = hi + lo (bf16 RNE pair):
//   A' = [h_hi | h_lo | h_hi] (K=192), B' = [W_hi ; W_hi ; W_lo]  (~2^-16 rel)
// Layouts (m89/m91): A/B-frag k = (lane>>4)*8+t, row/col = lane&15;
//   C/D: col = lane&15, row = (lane>>4)*4 + reg.
//
// ws: [0, 81.92MB) h2 | agg 3.2MB | stats 160B.  Bpk (245,760B) in d_out
// (consumed by K2 before K3a overwrites it; stream-ordered).

#define E_EDGES   320000
#define N_NODES_C 20000
#define D_C       40
#define A0_C      0.20412414523193154f   // 1/sqrt(24)
#define RSQRT3_C  0.57735026918962576f   // 1/sqrt(3)

typedef __attribute__((ext_vector_type(8))) short        bf16x8;
typedef __attribute__((ext_vector_type(4))) float        f32x4;
typedef __attribute__((ext_vector_type(4))) unsigned int u32x4;
typedef __attribute__((ext_vector_type(4))) int          i32x4;

__device__ __forceinline__ uint32_t rne16(uint32_t u) {
  return (u + 0x7fffu + ((u >> 16) & 1u)) >> 16;   // bf16 RNE, low 16 bits valid
}
__device__ __forceinline__ float4 ld4(const float* p) {
  return *reinterpret_cast<const float4*>(p);
}
__device__ __forceinline__ void st4(float* p, float a, float b, float c, float d) {
  *reinterpret_cast<float4*>(p) = make_float4(a, b, c, d);
}

// jp (processing order) -> original 16-col tile index. Phase A: w1 (jp 0..15),
// w4 (16..23); Phase B: w2 (24..31); Phase C: w3 (32..35).
__device__ __forceinline__ int cjp_map(int jp) {
  return jp < 16 ? jp : (jp < 24 ? jp + 12 : jp - 8);
}

// ---------------------------------------------------------------- B-pack
__global__ __launch_bounds__(256) void pack_kernel(
    const float* __restrict__ w2, const float* __restrict__ w1f,
    uint32_t* __restrict__ bpk)
{
  const int tid = blockIdx.x * 256 + threadIdx.x;   // 240*256 = 61440 dwords
  const int frag = tid >> 8;
  const int d    = tid & 255;
  const int lane = d >> 2, q = d & 3;
  const float* W; int stride, col, s;
  if (frag < 216) {
    const int jp = frag / 6; s = frag % 6;
    col = cjp_map(jp) * 16 + (lane & 15); W = w2; stride = 576;
  } else {
    const int f1 = frag - 216; const int nt = f1 / 6; s = f1 % 6;
    col = nt * 16 + (lane & 15); W = w1f; stride = 64;
  }
  uint32_t out = 0;
#pragma unroll
  for (int h = 0; h < 2; ++h) {
    const int t = q * 2 + h;
    const int kk = (lane >> 4) * 8 + t;
    const int krow = (s & 1) * 32 + kk;
    const float v = W[krow * stride + col];
    const uint32_t u = __float_as_uint(v);
    const uint32_t hb = rne16(u);
    uint32_t b16;
    if (s < 4) b16 = hb & 0xffffu;
    else {
      const float lo = v - __uint_as_float(hb << 16);
      b16 = rne16(__float_as_uint(lo)) & 0xffffu;
    }
    out |= b16 << (16 * h);
  }
  bpk[tid] = out;
}

// ---------------------------------------------------------------- K1: fc1 MFMA
__global__ __launch_bounds__(256, 4) void fc1_mfma_kernel(
    const float* __restrict__ ea, const uint32_t* __restrict__ bpk,
    const float* __restrict__ b1, uint32_t* __restrict__ h2g)
{
  const int tid = threadIdx.x;
  const int w = tid >> 6, lane = tid & 63;
  const int n = lane & 15, g = lane >> 4;
  const int rowB = blockIdx.x * 256 + w * 64;

  bf16x8 Ahi[4][2], Alo[4][2];
#pragma unroll
  for (int mt = 0; mt < 4; ++mt) {
    const int row = rowB + mt * 16 + n;
    const float4* epv = reinterpret_cast<const float4*>(ea + (size_t)row * 64);
#pragma unroll
    for (int s = 0; s < 2; ++s) {
      const float4 fa = epv[s * 8 + g * 2];
      const float4 fb = epv[s * 8 + g * 2 + 1];
      float f[8] = {fa.x, fa.y, fa.z, fa.w, fb.x, fb.y, fb.z, fb.w};
      uint32_t hw[4], lw[4];
#pragma unroll
      for (int j = 0; j < 4; ++j) {
        const uint32_t u0 = __float_as_uint(f[2 * j]);
        const uint32_t u1 = __float_as_uint(f[2 * j + 1]);
        const uint32_t h0 = rne16(u0), h1 = rne16(u1);
        const float l0 = f[2 * j]     - __uint_as_float(h0 << 16);
        const float l1 = f[2 * j + 1] - __uint_as_float(h1 << 16);
        hw[j] = (h0 & 0xffffu) | (h1 << 16);
        lw[j] = (rne16(__float_as_uint(l0)) & 0xffffu) |
                (rne16(__float_as_uint(l1)) << 16);
      }
      u32x4 hv = {hw[0], hw[1], hw[2], hw[3]};
      u32x4 lv = {lw[0], lw[1], lw[2], lw[3]};
      Ahi[mt][s] = __builtin_bit_cast(bf16x8, hv);
      Alo[mt][s] = __builtin_bit_cast(bf16x8, lv);
    }
  }

  const u32x4* bp4 = reinterpret_cast<const u32x4*>(bpk);
#pragma unroll 1
  for (int nt = 0; nt < 4; ++nt) {
    u32x4 bfr[6];
#pragma unroll
    for (int s = 0; s < 6; ++s) bfr[s] = bp4[(216 + nt * 6 + s) * 64 + lane];
    f32x4 acc[4];
#pragma unroll
    for (int mt = 0; mt < 4; ++mt) acc[mt] = (f32x4)(0.0f);
#pragma unroll
    for (int s = 0; s < 6; ++s) {
      const bf16x8 B = __builtin_bit_cast(bf16x8, bfr[s]);
#pragma unroll
      for (int mt = 0; mt < 4; ++mt) {
        const bf16x8 A = (s < 2) ? Ahi[mt][s] : (s < 4 ? Alo[mt][s - 2] : Ahi[mt][s - 4]);
        acc[mt] = __builtin_amdgcn_mfma_f32_16x16x32_bf16(A, B, acc[mt], 0, 0, 0);
      }
    }
    const float bv = b1[nt * 16 + n];
#pragma unroll
    for (int mt = 0; mt < 4; ++mt) {
#pragma unroll
      for (int r = 0; r < 4; ++r) {
        const float v = fmaxf(acc[mt][r] + bv, 0.0f);
        const uint32_t hb = rne16(__float_as_uint(v));
        const float lo = v - __uint_as_float(hb << 16);
        const uint32_t lb = rne16(__float_as_uint(lo)) & 0xffffu;
        const int row = rowB + mt * 16 + g * 4 + r;
        h2g[(size_t)row * 64 + nt * 16 + n] = (hb & 0xffffu) | (lb << 16);
      }
    }
  }
}

// ---------------------------------------------------------------- K2: fc2+TP
// Phase-split coefficient staging: ubuf holds {xs[4][16][64] | dt[4][8][64]}
// for phases A+B, then is re-staged as xv[4][8][3][64] for phase C.
__global__ __launch_bounds__(256, 4) void edge_mfma_kernel(
    const uint32_t* __restrict__ h2g, const uint32_t* __restrict__ bpk,
    const float* __restrict__ b2, const float* __restrict__ na,
    const float* __restrict__ sh, const int* __restrict__ ei,
    float* __restrict__ agg)
{
  __shared__ __align__(16) float ubuf[6144];     // 24,576 B union buffer
  __shared__ __align__(16) float shsT[4][64];
  __shared__ __align__(16) float shvT[4][3][64];
  __shared__ __align__(16) int   dstT[4][64];
  __shared__ float b2s[576];
  // total LDS = 24576 + 1024 + 3072 + 1024 + 2304 = 32,000 B -> 4 blocks/CU

  const int tid = threadIdx.x;
  const int w = tid >> 6, lane = tid & 63;
  const int n = lane & 15, g = lane >> 4;
  const int eBlock = blockIdx.x * 256;

  const int e = eBlock + tid;
  const int src = ei[e];                          // kept live for xv re-stage
  // ---- stage persistent + xs + dt
  {
    dstT[w][lane] = ei[E_EDGES + e];
    const float4 shq = ld4(sh + (size_t)e * 4);
    shsT[w][lane] = shq.x;
    shvT[w][0][lane] = shq.y; shvT[w][1][lane] = shq.z; shvT[w][2][lane] = shq.w;
    const float* nas = na + (size_t)src * D_C;
    float x[40];
#pragma unroll
    for (int i = 0; i < 10; ++i) {
      const float4 v = ld4(nas + i * 4);
      x[i * 4] = v.x; x[i * 4 + 1] = v.y; x[i * 4 + 2] = v.z; x[i * 4 + 3] = v.w;
    }
#pragma unroll
    for (int u = 0; u < 16; ++u) ubuf[(w * 16 + u) * 64 + lane] = x[u];   // xs
#pragma unroll
    for (int u = 0; u < 8; ++u) {
      const float a = x[16 + u * 3], b = x[16 + u * 3 + 1], c = x[16 + u * 3 + 2];
      ubuf[4096 + (w * 8 + u) * 64 + lane] =
          (a * shq.y + b * shq.z + c * shq.w) * RSQRT3_C;                 // dt
    }
    if (tid < 144)
      reinterpret_cast<float4*>(b2s)[tid] = reinterpret_cast<const float4*>(b2)[tid];
  }
  __syncthreads();

  // ---- A fragments (read h2 once; hi-frags reused for ks 4,5)
  bf16x8 Ahi[4][2], Alo[4][2];
#pragma unroll
  for (int mt = 0; mt < 4; ++mt) {
    const int row = eBlock + w * 64 + mt * 16 + n;
    const u32x4* hp = reinterpret_cast<const u32x4*>(h2g + (size_t)row * 64);
#pragma unroll
    for (int s = 0; s < 2; ++s) {
      const u32x4 qa = hp[s * 8 + g * 2];
      const u32x4 qb = hp[s * 8 + g * 2 + 1];
      u32x4 hv, lv;
      hv[0] = (qa[0] & 0xffffu) | (qa[1] << 16);
      hv[1] = (qa[2] & 0xffffu) | (qa[3] << 16);
      hv[2] = (qb[0] & 0xffffu) | (qb[1] << 16);
      hv[3] = (qb[2] & 0xffffu) | (qb[3] << 16);
      lv[0] = (qa[0] >> 16) | (qa[1] & 0xffff0000u);
      lv[1] = (qa[2] >> 16) | (qa[3] & 0xffff0000u);
      lv[2] = (qb[0] >> 16) | (qb[1] & 0xffff0000u);
      lv[3] = (qb[2] >> 16) | (qb[3] & 0xffff0000u);
      Ahi[mt][s] = __builtin_bit_cast(bf16x8, hv);
      Alo[mt][s] = __builtin_bit_cast(bf16x8, lv);
    }
  }

  f32x4 shsv[4]; i32x4 dstv[4];
#pragma unroll
  for (int mt = 0; mt < 4; ++mt) {
    shsv[mt] = *reinterpret_cast<const f32x4*>(&shsT[w][mt * 16 + g * 4]);
    dstv[mt] = *reinterpret_cast<const i32x4*>(&dstT[w][mt * 16 + g * 4]);
  }

  const u32x4* bp4 = reinterpret_cast<const u32x4*>(bpk);

#define TILE_ACC(jp_)                                                          \
  f32x4 acc[4];                                                                \
  {                                                                            \
    u32x4 bfr[6];                                                              \
    _Pragma("unroll")                                                          \
    for (int s = 0; s < 6; ++s) bfr[s] = bp4[((jp_) * 6 + s) * 64 + lane];     \
    _Pragma("unroll")                                                          \
    for (int mt = 0; mt < 4; ++mt) acc[mt] = (f32x4)(0.0f);                    \
    _Pragma("unroll")                                                          \
    for (int s = 0; s < 6; ++s) {                                              \
      const bf16x8 B = __builtin_bit_cast(bf16x8, bfr[s]);                     \
      _Pragma("unroll")                                                        \
      for (int mt = 0; mt < 4; ++mt) {                                         \
        const bf16x8 A = (s < 2) ? Ahi[mt][s]                                  \
                                 : (s < 4 ? Alo[mt][s - 2] : Ahi[mt][s - 4]);  \
        acc[mt] = __builtin_amdgcn_mfma_f32_16x16x32_bf16(A, B, acc[mt], 0, 0, 0); \
      }                                                                        \
    }                                                                          \
    const float bv = b2s[cjp_map(jp_) * 16 + n];                               \
    _Pragma("unroll")                                                          \
    for (int mt = 0; mt < 4; ++mt) acc[mt] = acc[mt] + bv;                     \
  }

  // ---- phase A: out0 (w1: coef xs*shs, w4: coef dt)
  f32x4 out0[4];
#pragma unroll
  for (int mt = 0; mt < 4; ++mt) out0[mt] = (f32x4)(0.0f);
#pragma unroll 4
  for (int jp = 0; jp < 16; ++jp) {
    TILE_ACC(jp);
#pragma unroll
    for (int mt = 0; mt < 4; ++mt) {
      const f32x4 xsv = *reinterpret_cast<const f32x4*>(
          &ubuf[(w * 16 + jp) * 64 + mt * 16 + g * 4]);
      out0[mt] += acc[mt] * shsv[mt] * xsv;
    }
  }
#pragma unroll 4
  for (int jp = 16; jp < 24; ++jp) {
    TILE_ACC(jp);
#pragma unroll
    for (int mt = 0; mt < 4; ++mt) {
      const f32x4 dv = *reinterpret_cast<const f32x4*>(
          &ubuf[4096 + (w * 8 + (jp - 16)) * 64 + mt * 16 + g * 4]);
      out0[mt] += acc[mt] * dv;
    }
  }
#pragma unroll
  for (int mt = 0; mt < 4; ++mt)
#pragma unroll
    for (int r = 0; r < 4; ++r)
      atomicAdd(&agg[(size_t)dstv[mt][r] * D_C + n], out0[mt][r] * A0_C);

  // ---- phase B: s2 (w2: coef xs, shv folded at finalize)
  f32x4 s2[4];
#pragma unroll
  for (int mt = 0; mt < 4; ++mt) s2[mt] = (f32x4)(0.0f);
#pragma unroll 4
  for (int jp = 24; jp < 32; ++jp) {
    TILE_ACC(jp);
    const int u0 = (jp - 24) * 2 + (n >> 3);
#pragma unroll
    for (int mt = 0; mt < 4; ++mt) {
      const f32x4 xsv = *reinterpret_cast<const f32x4*>(
          &ubuf[(w * 16 + u0) * 64 + mt * 16 + g * 4]);
      s2[mt] += acc[mt] * xsv;
    }
  }

  // ---- re-stage: xs/dt -> xv (phase C coefficients) in the SAME buffer
  __syncthreads();                                  // all xs/dt reads done
  {
    const float* nav = na + (size_t)src * D_C + 16;
    float xv[24];
#pragma unroll
    for (int i = 0; i < 6; ++i) {
      const float4 v = ld4(nav + i * 4);
      xv[i * 4] = v.x; xv[i * 4 + 1] = v.y; xv[i * 4 + 2] = v.z; xv[i * 4 + 3] = v.w;
    }
#pragma unroll
    for (int u = 0; u < 8; ++u)
#pragma unroll
      for (int m = 0; m < 3; ++m)
        ubuf[((w * 8 + u) * 3 + m) * 64 + lane] = xv[u * 3 + m];
  }
  __syncthreads();

  // ---- phase C: s3[m] (w3: coef xv[u][m], shs folded at finalize)
  f32x4 s3[3][4];
#pragma unroll
  for (int m = 0; m < 3; ++m)
#pragma unroll
    for (int mt = 0; mt < 4; ++mt) s3[m][mt] = (f32x4)(0.0f);
#pragma unroll 2
  for (int jp = 32; jp < 36; ++jp) {
    TILE_ACC(jp);
    const int u0 = (jp - 32) * 2 + (n >> 3);
#pragma unroll
    for (int mt = 0; mt < 4; ++mt)
#pragma unroll
      for (int m = 0; m < 3; ++m) {
        const f32x4 xvv = *reinterpret_cast<const f32x4*>(
            &ubuf[((w * 8 + u0) * 3 + m) * 64 + mt * 16 + g * 4]);
        s3[m][mt] += acc[mt] * xvv;
      }
  }

  // ---- finalize out1: lanes n and n^8 hold the u-split halves -> combine
#pragma unroll
  for (int mt = 0; mt < 4; ++mt)
#pragma unroll
    for (int m = 0; m < 3; ++m) {
      const f32x4 shvv = *reinterpret_cast<const f32x4*>(&shvT[w][m][mt * 16 + g * 4]);
      const f32x4 o = (s2[mt] * shvv + s3[m][mt] * shsv[mt]) * A0_C;
#pragma unroll
      for (int r = 0; r < 4; ++r) {
        float v = o[r];
        v += __shfl_xor(v, 8, 64);
        if (n < 8)
          atomicAdd(&agg[(size_t)dstv[mt][r] * D_C + 16 + n * 3 + m], v);
      }
    }
#undef TILE_ACC
}

// -------------------------------------------- K3a: residual add + BN statistics
__global__ __launch_bounds__(256) void resid_stats_kernel(
    const float* __restrict__ agg, const float* __restrict__ na,
    float* __restrict__ outp, float* __restrict__ stats)
{
  const int nn = blockIdx.x * 256 + threadIdx.x;
  float v[40];
  if (nn < N_NODES_C) {
    const float* ap = agg + (size_t)nn * D_C;
    const float* np = na + (size_t)nn * D_C;
#pragma unroll
    for (int i = 0; i < 10; ++i) {
      const float4 a = ld4(ap + i * 4);
      const float4 b = ld4(np + i * 4);
      v[i * 4] = a.x + b.x; v[i * 4 + 1] = a.y + b.y;
      v[i * 4 + 2] = a.z + b.z; v[i * 4 + 3] = a.w + b.w;
    }
    float* op = outp + (size_t)nn * D_C;
#pragma unroll
    for (int i = 0; i < 10; ++i)
      st4(op + i * 4, v[i * 4], v[i * 4 + 1], v[i * 4 + 2], v[i * 4 + 3]);
  } else {
#pragma unroll
    for (int i = 0; i < 40; ++i) v[i] = 0.f;
  }
  float red[40];
#pragma unroll
  for (int c = 0; c < 16; ++c) { red[c] = v[c]; red[16 + c] = v[c] * v[c]; }
#pragma unroll
  for (int u = 0; u < 8; ++u) {
    const float a = v[16 + u * 3], b = v[16 + u * 3 + 1], c = v[16 + u * 3 + 2];
    red[32 + u] = a * a + b * b + c * c;
  }
#pragma unroll
  for (int i = 0; i < 40; ++i) {
    float x = red[i];
#pragma unroll
    for (int off = 32; off > 0; off >>= 1) x += __shfl_xor(x, off, 64);
    red[i] = x;
  }
  if ((threadIdx.x & 63) == 0) {
#pragma unroll
    for (int i = 0; i < 40; ++i) atomicAdd(stats + i, red[i]);
  }
}

// ------------------------------------------------------------ K3b: BN apply
__global__ __launch_bounds__(256) void bn_apply_kernel(
    float* __restrict__ outp, const float* __restrict__ stats,
    const float* __restrict__ gs, const float* __restrict__ bsv,
    const float* __restrict__ gv)
{
  __shared__ float A[16], B[16], AV[8];
  const int tid = threadIdx.x;
  if (tid < 16) {
    const float s = stats[tid], q = stats[16 + tid];
    const float mu = s * (1.f / 20000.f);
    const float var = q * (1.f / 20000.f) - mu * mu;
    const float a = rsqrtf(var + 1e-5f) * gs[tid];
    A[tid] = a;
    B[tid] = bsv[tid] - mu * a;
  } else if (tid < 24) {
    const int u = tid - 16;
    const float vn = stats[32 + u] * (1.f / (20000.f * 3.f));
    AV[u] = rsqrtf(vn + 1e-5f) * gv[u];
  }
  __syncthreads();
  const int nn = blockIdx.x * 256 + tid;
  if (nn < N_NODES_C) {
    float* op = outp + (size_t)nn * D_C;
    float v[40];
#pragma unroll
    for (int i = 0; i < 10; ++i) {
      const float4 t = ld4(op + i * 4);
      v[i * 4] = t.x; v[i * 4 + 1] = t.y; v[i * 4 + 2] = t.z; v[i * 4 + 3] = t.w;
    }
#pragma unroll
    for (int c = 0; c < 16; ++c) v[c] = v[c] * A[c] + B[c];
#pragma unroll
    for (int u = 0; u < 8; ++u) {
      const float a = AV[u];
      v[16 + u * 3] *= a; v[16 + u * 3 + 1] *= a; v[16 + u * 3 + 2] *= a;
    }
#pragma unroll
    for (int i = 0; i < 10; ++i)
      st4(op + i * 4, v[i * 4], v[i * 4 + 1], v[i * 4 + 2], v[i * 4 + 3]);
  }
}

// ---------------------------------------------------------------- launcher
extern "C" void kernel_launch(void* const* d_in, const int* in_sizes, int n_in,
                              void* d_out, int out_size, void* d_ws, size_t ws_size,
                              hipStream_t stream) {
  const float* node_attr = (const float*)d_in[0];
  const float* edge_attr = (const float*)d_in[1];
  const float* edge_sh   = (const float*)d_in[2];
  const float* fc1_w     = (const float*)d_in[3];
  const float* fc1_b     = (const float*)d_in[4];
  const float* fc2_w     = (const float*)d_in[5];
  const float* fc2_b     = (const float*)d_in[6];
  const float* gs        = (const float*)d_in[7];
  const float* bs        = (const float*)d_in[8];
  const float* gv        = (const float*)d_in[9];
  const int*   ei        = (const int*)d_in[10];
  float* out = (float*)d_out;

  char* ws = (char*)d_ws;
  uint32_t* h2   = (uint32_t*)(ws);                      // 320000*64*4 = 81,920,000
  float*    agg  = (float*)(ws + 81920000);              // 20000*40*4  =  3,200,000
  float*    stats= (float*)(ws + 81920000 + 3200000);    // 40*4
  uint32_t* bpk  = (uint32_t*)d_out;                     // 245,760 B scratch

  hipMemsetAsync(agg, 0, 3200000 + 160, stream);
  pack_kernel<<<240, 256, 0, stream>>>(fc2_w, fc1_w, bpk);
  fc1_mfma_kernel<<<1250, 256, 0, stream>>>(edge_attr, bpk, fc1_b, h2);
  edge_mfma_kernel<<<1250, 256, 0, stream>>>(h2, bpk, fc2_b, node_attr, edge_sh, ei, agg);
  resid_stats_kernel<<<79, 256, 0, stream>>>(agg, node_attr, out, stats);
  bn_apply_kernel<<<79, 256, 0, stream>>>(out, stats, gs, bs, gv);
}

// Round 11
// 493.408 us; speedup vs baseline: 1.2429x; 1.2429x over previous
//
#include <hip/hip_runtime.h>
#include <stdint.h>

// TensorProductConvLayer — round 11 (== round 10 resubmit; R10 bench was an
// infra GPUAcquisitionTimeout, kernel never ran).
//
// R9 post-mortem: __launch_bounds__(256,4) capped unified VGPR+AGPR at 128;
// live state ~150+ -> compiler spilled (VGPR_Count 64, FETCH 68->560MB,
// WRITE 110->390MB, MfmaUtil 15.5->8.5%, edge 185->337us). Occupancy DID
// rise (19->38.5%) proving the LDS phase-split worked. This round keeps the
// 32KB LDS and reverts to (256,2) (R8-proven 116 VGPR, no spill):
// occupancy comes from actual usage (116<=128 -> 4 waves/SIMD, LDS -> 5
// blocks/CU) => 4 blocks/CU without forcing the allocator.
//
// Precision: A and B split h = hi + lo (bf16 RNE pair):
//   A' = [h_hi | h_lo | h_hi] (K=192), B' = [W_hi ; W_hi ; W_lo]  (~2^-16 rel)
// Layouts (m89/m91): A/B-frag k = (lane>>4)*8+t, row/col = lane&15;
//   C/D: col = lane&15, row = (lane>>4)*4 + reg.
//
// ws: [0, 81.92MB) h2 | agg 3.2MB | stats 160B.  Bpk (245,760B) in d_out
// (consumed by K2 before K3a overwrites it; stream-ordered).

#define E_EDGES   320000
#define N_NODES_C 20000
#define D_C       40
#define A0_C      0.20412414523193154f   // 1/sqrt(24)
#define RSQRT3_C  0.57735026918962576f   // 1/sqrt(3)

typedef __attribute__((ext_vector_type(8))) short        bf16x8;
typedef __attribute__((ext_vector_type(4))) float        f32x4;
typedef __attribute__((ext_vector_type(4))) unsigned int u32x4;
typedef __attribute__((ext_vector_type(4))) int          i32x4;

__device__ __forceinline__ uint32_t rne16(uint32_t u) {
  return (u + 0x7fffu + ((u >> 16) & 1u)) >> 16;   // bf16 RNE, low 16 bits valid
}
__device__ __forceinline__ float4 ld4(const float* p) {
  return *reinterpret_cast<const float4*>(p);
}
__device__ __forceinline__ void st4(float* p, float a, float b, float c, float d) {
  *reinterpret_cast<float4*>(p) = make_float4(a, b, c, d);
}

// jp (processing order) -> original 16-col tile index. Phase A: w1 (jp 0..15),
// w4 (16..23); Phase B: w2 (24..31); Phase C: w3 (32..35).
__device__ __forceinline__ int cjp_map(int jp) {
  return jp < 16 ? jp : (jp < 24 ? jp + 12 : jp - 8);
}

// ---------------------------------------------------------------- B-pack
__global__ __launch_bounds__(256) void pack_kernel(
    const float* __restrict__ w2, const float* __restrict__ w1f,
    uint32_t* __restrict__ bpk)
{
  const int tid = blockIdx.x * 256 + threadIdx.x;   // 240*256 = 61440 dwords
  const int frag = tid >> 8;
  const int d    = tid & 255;
  const int lane = d >> 2, q = d & 3;
  const float* W; int stride, col, s;
  if (frag < 216) {
    const int jp = frag / 6; s = frag % 6;
    col = cjp_map(jp) * 16 + (lane & 15); W = w2; stride = 576;
  } else {
    const int f1 = frag - 216; const int nt = f1 / 6; s = f1 % 6;
    col = nt * 16 + (lane & 15); W = w1f; stride = 64;
  }
  uint32_t out = 0;
#pragma unroll
  for (int h = 0; h < 2; ++h) {
    const int t = q * 2 + h;
    const int kk = (lane >> 4) * 8 + t;
    const int krow = (s & 1) * 32 + kk;
    const float v = W[krow * stride + col];
    const uint32_t u = __float_as_uint(v);
    const uint32_t hb = rne16(u);
    uint32_t b16;
    if (s < 4) b16 = hb & 0xffffu;
    else {
      const float lo = v - __uint_as_float(hb << 16);
      b16 = rne16(__float_as_uint(lo)) & 0xffffu;
    }
    out |= b16 << (16 * h);
  }
  bpk[tid] = out;
}

// ---------------------------------------------------------------- K1: fc1 MFMA
__global__ __launch_bounds__(256, 2) void fc1_mfma_kernel(
    const float* __restrict__ ea, const uint32_t* __restrict__ bpk,
    const float* __restrict__ b1, uint32_t* __restrict__ h2g)
{
  const int tid = threadIdx.x;
  const int w = tid >> 6, lane = tid & 63;
  const int n = lane & 15, g = lane >> 4;
  const int rowB = blockIdx.x * 256 + w * 64;

  bf16x8 Ahi[4][2], Alo[4][2];
#pragma unroll
  for (int mt = 0; mt < 4; ++mt) {
    const int row = rowB + mt * 16 + n;
    const float4* epv = reinterpret_cast<const float4*>(ea + (size_t)row * 64);
#pragma unroll
    for (int s = 0; s < 2; ++s) {
      const float4 fa = epv[s * 8 + g * 2];
      const float4 fb = epv[s * 8 + g * 2 + 1];
      float f[8] = {fa.x, fa.y, fa.z, fa.w, fb.x, fb.y, fb.z, fb.w};
      uint32_t hw[4], lw[4];
#pragma unroll
      for (int j = 0; j < 4; ++j) {
        const uint32_t u0 = __float_as_uint(f[2 * j]);
        const uint32_t u1 = __float_as_uint(f[2 * j + 1]);
        const uint32_t h0 = rne16(u0), h1 = rne16(u1);
        const float l0 = f[2 * j]     - __uint_as_float(h0 << 16);
        const float l1 = f[2 * j + 1] - __uint_as_float(h1 << 16);
        hw[j] = (h0 & 0xffffu) | (h1 << 16);
        lw[j] = (rne16(__float_as_uint(l0)) & 0xffffu) |
                (rne16(__float_as_uint(l1)) << 16);
      }
      u32x4 hv = {hw[0], hw[1], hw[2], hw[3]};
      u32x4 lv = {lw[0], lw[1], lw[2], lw[3]};
      Ahi[mt][s] = __builtin_bit_cast(bf16x8, hv);
      Alo[mt][s] = __builtin_bit_cast(bf16x8, lv);
    }
  }

  const u32x4* bp4 = reinterpret_cast<const u32x4*>(bpk);
#pragma unroll 1
  for (int nt = 0; nt < 4; ++nt) {
    u32x4 bfr[6];
#pragma unroll
    for (int s = 0; s < 6; ++s) bfr[s] = bp4[(216 + nt * 6 + s) * 64 + lane];
    f32x4 acc[4];
#pragma unroll
    for (int mt = 0; mt < 4; ++mt) acc[mt] = (f32x4)(0.0f);
#pragma unroll
    for (int s = 0; s < 6; ++s) {
      const bf16x8 B = __builtin_bit_cast(bf16x8, bfr[s]);
#pragma unroll
      for (int mt = 0; mt < 4; ++mt) {
        const bf16x8 A = (s < 2) ? Ahi[mt][s] : (s < 4 ? Alo[mt][s - 2] : Ahi[mt][s - 4]);
        acc[mt] = __builtin_amdgcn_mfma_f32_16x16x32_bf16(A, B, acc[mt], 0, 0, 0);
      }
    }
    const float bv = b1[nt * 16 + n];
#pragma unroll
    for (int mt = 0; mt < 4; ++mt) {
#pragma unroll
      for (int r = 0; r < 4; ++r) {
        const float v = fmaxf(acc[mt][r] + bv, 0.0f);
        const uint32_t hb = rne16(__float_as_uint(v));
        const float lo = v - __uint_as_float(hb << 16);
        const uint32_t lb = rne16(__float_as_uint(lo)) & 0xffffu;
        const int row = rowB + mt * 16 + g * 4 + r;
        h2g[(size_t)row * 64 + nt * 16 + n] = (hb & 0xffffu) | (lb << 16);
      }
    }
  }
}

// ---------------------------------------------------------------- K2: fc2+TP
// Phase-split coefficient staging: ubuf holds {xs[4][16][64] | dt[4][8][64]}
// for phases A+B, then is re-staged as xv[4][8][3][64] for phase C.
__global__ __launch_bounds__(256, 2) void edge_mfma_kernel(
    const uint32_t* __restrict__ h2g, const uint32_t* __restrict__ bpk,
    const float* __restrict__ b2, const float* __restrict__ na,
    const float* __restrict__ sh, const int* __restrict__ ei,
    float* __restrict__ agg)
{
  __shared__ __align__(16) float ubuf[6144];     // 24,576 B union buffer
  __shared__ __align__(16) float shsT[4][64];
  __shared__ __align__(16) float shvT[4][3][64];
  __shared__ __align__(16) int   dstT[4][64];
  __shared__ float b2s[576];
  // total LDS = 24576 + 1024 + 3072 + 1024 + 2304 = 32,000 B -> 5 blocks by
  // LDS; occupancy gated by actual VGPR (~116 -> 4 waves/SIMD -> 4 blocks/CU)

  const int tid = threadIdx.x;
  const int w = tid >> 6, lane = tid & 63;
  const int n = lane & 15, g = lane >> 4;
  const int eBlock = blockIdx.x * 256;

  const int e = eBlock + tid;
  const int src = ei[e];                          // kept live for xv re-stage
  // ---- stage persistent + xs + dt
  {
    dstT[w][lane] = ei[E_EDGES + e];
    const float4 shq = ld4(sh + (size_t)e * 4);
    shsT[w][lane] = shq.x;
    shvT[w][0][lane] = shq.y; shvT[w][1][lane] = shq.z; shvT[w][2][lane] = shq.w;
    const float* nas = na + (size_t)src * D_C;
    float x[40];
#pragma unroll
    for (int i = 0; i < 10; ++i) {
      const float4 v = ld4(nas + i * 4);
      x[i * 4] = v.x; x[i * 4 + 1] = v.y; x[i * 4 + 2] = v.z; x[i * 4 + 3] = v.w;
    }
#pragma unroll
    for (int u = 0; u < 16; ++u) ubuf[(w * 16 + u) * 64 + lane] = x[u];   // xs
#pragma unroll
    for (int u = 0; u < 8; ++u) {
      const float a = x[16 + u * 3], b = x[16 + u * 3 + 1], c = x[16 + u * 3 + 2];
      ubuf[4096 + (w * 8 + u) * 64 + lane] =
          (a * shq.y + b * shq.z + c * shq.w) * RSQRT3_C;                 // dt
    }
    if (tid < 144)
      reinterpret_cast<float4*>(b2s)[tid] = reinterpret_cast<const float4*>(b2)[tid];
  }
  __syncthreads();

  // ---- A fragments (read h2 once; hi-frags reused for ks 4,5)
  bf16x8 Ahi[4][2], Alo[4][2];
#pragma unroll
  for (int mt = 0; mt < 4; ++mt) {
    const int row = eBlock + w * 64 + mt * 16 + n;
    const u32x4* hp = reinterpret_cast<const u32x4*>(h2g + (size_t)row * 64);
#pragma unroll
    for (int s = 0; s < 2; ++s) {
      const u32x4 qa = hp[s * 8 + g * 2];
      const u32x4 qb = hp[s * 8 + g * 2 + 1];
      u32x4 hv, lv;
      hv[0] = (qa[0] & 0xffffu) | (qa[1] << 16);
      hv[1] = (qa[2] & 0xffffu) | (qa[3] << 16);
      hv[2] = (qb[0] & 0xffffu) | (qb[1] << 16);
      hv[3] = (qb[2] & 0xffffu) | (qb[3] << 16);
      lv[0] = (qa[0] >> 16) | (qa[1] & 0xffff0000u);
      lv[1] = (qa[2] >> 16) | (qa[3] & 0xffff0000u);
      lv[2] = (qb[0] >> 16) | (qb[1] & 0xffff0000u);
      lv[3] = (qb[2] >> 16) | (qb[3] & 0xffff0000u);
      Ahi[mt][s] = __builtin_bit_cast(bf16x8, hv);
      Alo[mt][s] = __builtin_bit_cast(bf16x8, lv);
    }
  }

  f32x4 shsv[4]; i32x4 dstv[4];
#pragma unroll
  for (int mt = 0; mt < 4; ++mt) {
    shsv[mt] = *reinterpret_cast<const f32x4*>(&shsT[w][mt * 16 + g * 4]);
    dstv[mt] = *reinterpret_cast<const i32x4*>(&dstT[w][mt * 16 + g * 4]);
  }

  const u32x4* bp4 = reinterpret_cast<const u32x4*>(bpk);

#define TILE_ACC(jp_)                                                          \
  f32x4 acc[4];                                                                \
  {                                                                            \
    u32x4 bfr[6];                                                              \
    _Pragma("unroll")                                                          \
    for (int s = 0; s < 6; ++s) bfr[s] = bp4[((jp_) * 6 + s) * 64 + lane];     \
    _Pragma("unroll")                                                          \
    for (int mt = 0; mt < 4; ++mt) acc[mt] = (f32x4)(0.0f);                    \
    _Pragma("unroll")                                                          \
    for (int s = 0; s < 6; ++s) {                                              \
      const bf16x8 B = __builtin_bit_cast(bf16x8, bfr[s]);                     \
      _Pragma("unroll")                                                        \
      for (int mt = 0; mt < 4; ++mt) {                                         \
        const bf16x8 A = (s < 2) ? Ahi[mt][s]                                  \
                                 : (s < 4 ? Alo[mt][s - 2] : Ahi[mt][s - 4]);  \
        acc[mt] = __builtin_amdgcn_mfma_f32_16x16x32_bf16(A, B, acc[mt], 0, 0, 0); \
      }                                                                        \
    }                                                                          \
    const float bv = b2s[cjp_map(jp_) * 16 + n];                               \
    _Pragma("unroll")                                                          \
    for (int mt = 0; mt < 4; ++mt) acc[mt] = acc[mt] + bv;                     \
  }

  // ---- phase A: out0 (w1: coef xs*shs, w4: coef dt)
  f32x4 out0[4];
#pragma unroll
  for (int mt = 0; mt < 4; ++mt) out0[mt] = (f32x4)(0.0f);
#pragma unroll 4
  for (int jp = 0; jp < 16; ++jp) {
    TILE_ACC(jp);
#pragma unroll
    for (int mt = 0; mt < 4; ++mt) {
      const f32x4 xsv = *reinterpret_cast<const f32x4*>(
          &ubuf[(w * 16 + jp) * 64 + mt * 16 + g * 4]);
      out0[mt] += acc[mt] * shsv[mt] * xsv;
    }
  }
#pragma unroll 4
  for (int jp = 16; jp < 24; ++jp) {
    TILE_ACC(jp);
#pragma unroll
    for (int mt = 0; mt < 4; ++mt) {
      const f32x4 dv = *reinterpret_cast<const f32x4*>(
          &ubuf[4096 + (w * 8 + (jp - 16)) * 64 + mt * 16 + g * 4]);
      out0[mt] += acc[mt] * dv;
    }
  }
#pragma unroll
  for (int mt = 0; mt < 4; ++mt)
#pragma unroll
    for (int r = 0; r < 4; ++r)
      atomicAdd(&agg[(size_t)dstv[mt][r] * D_C + n], out0[mt][r] * A0_C);

  // ---- phase B: s2 (w2: coef xs, shv folded at finalize)
  f32x4 s2[4];
#pragma unroll
  for (int mt = 0; mt < 4; ++mt) s2[mt] = (f32x4)(0.0f);
#pragma unroll 4
  for (int jp = 24; jp < 32; ++jp) {
    TILE_ACC(jp);
    const int u0 = (jp - 24) * 2 + (n >> 3);
#pragma unroll
    for (int mt = 0; mt < 4; ++mt) {
      const f32x4 xsv = *reinterpret_cast<const f32x4*>(
          &ubuf[(w * 16 + u0) * 64 + mt * 16 + g * 4]);
      s2[mt] += acc[mt] * xsv;
    }
  }

  // ---- re-stage: xs/dt -> xv (phase C coefficients) in the SAME buffer
  __syncthreads();                                  // all xs/dt reads done
  {
    const float* nav = na + (size_t)src * D_C + 16;
    float xv[24];
#pragma unroll
    for (int i = 0; i < 6; ++i) {
      const float4 v = ld4(nav + i * 4);
      xv[i * 4] = v.x; xv[i * 4 + 1] = v.y; xv[i * 4 + 2] = v.z; xv[i * 4 + 3] = v.w;
    }
#pragma unroll
    for (int u = 0; u < 8; ++u)
#pragma unroll
      for (int m = 0; m < 3; ++m)
        ubuf[((w * 8 + u) * 3 + m) * 64 + lane] = xv[u * 3 + m];
  }
  __syncthreads();

  // ---- phase C: s3[m] (w3: coef xv[u][m], shs folded at finalize)
  f32x4 s3[3][4];
#pragma unroll
  for (int m = 0; m < 3; ++m)
#pragma unroll
    for (int mt = 0; mt < 4; ++mt) s3[m][mt] = (f32x4)(0.0f);
#pragma unroll 2
  for (int jp = 32; jp < 36; ++jp) {
    TILE_ACC(jp);
    const int u0 = (jp - 32) * 2 + (n >> 3);
#pragma unroll
    for (int mt = 0; mt < 4; ++mt)
#pragma unroll
      for (int m = 0; m < 3; ++m) {
        const f32x4 xvv = *reinterpret_cast<const f32x4*>(
            &ubuf[((w * 8 + u0) * 3 + m) * 64 + mt * 16 + g * 4]);
        s3[m][mt] += acc[mt] * xvv;
      }
  }

  // ---- finalize out1: lanes n and n^8 hold the u-split halves -> combine
#pragma unroll
  for (int mt = 0; mt < 4; ++mt)
#pragma unroll
    for (int m = 0; m < 3; ++m) {
      const f32x4 shvv = *reinterpret_cast<const f32x4*>(&shvT[w][m][mt * 16 + g * 4]);
      const f32x4 o = (s2[mt] * shvv + s3[m][mt] * shsv[mt]) * A0_C;
#pragma unroll
      for (int r = 0; r < 4; ++r) {
        float v = o[r];
        v += __shfl_xor(v, 8, 64);
        if (n < 8)
          atomicAdd(&agg[(size_t)dstv[mt][r] * D_C + 16 + n * 3 + m], v);
      }
    }
#undef TILE_ACC
}

// -------------------------------------------- K3a: residual add + BN statistics
__global__ __launch_bounds__(256) void resid_stats_kernel(
    const float* __restrict__ agg, const float* __restrict__ na,
    float* __restrict__ outp, float* __restrict__ stats)
{
  const int nn = blockIdx.x * 256 + threadIdx.x;
  float v[40];
  if (nn < N_NODES_C) {
    const float* ap = agg + (size_t)nn * D_C;
    const float* np = na + (size_t)nn * D_C;
#pragma unroll
    for (int i = 0; i < 10; ++i) {
      const float4 a = ld4(ap + i * 4);
      const float4 b = ld4(np + i * 4);
      v[i * 4] = a.x + b.x; v[i * 4 + 1] = a.y + b.y;
      v[i * 4 + 2] = a.z + b.z; v[i * 4 + 3] = a.w + b.w;
    }
    float* op = outp + (size_t)nn * D_C;
#pragma unroll
    for (int i = 0; i < 10; ++i)
      st4(op + i * 4, v[i * 4], v[i * 4 + 1], v[i * 4 + 2], v[i * 4 + 3]);
  } else {
#pragma unroll
    for (int i = 0; i < 40; ++i) v[i] = 0.f;
  }
  float red[40];
#pragma unroll
  for (int c = 0; c < 16; ++c) { red[c] = v[c]; red[16 + c] = v[c] * v[c]; }
#pragma unroll
  for (int u = 0; u < 8; ++u) {
    const float a = v[16 + u * 3], b = v[16 + u * 3 + 1], c = v[16 + u * 3 + 2];
    red[32 + u] = a * a + b * b + c * c;
  }
#pragma unroll
  for (int i = 0; i < 40; ++i) {
    float x = red[i];
#pragma unroll
    for (int off = 32; off > 0; off >>= 1) x += __shfl_xor(x, off, 64);
    red[i] = x;
  }
  if ((threadIdx.x & 63) == 0) {
#pragma unroll
    for (int i = 0; i < 40; ++i) atomicAdd(stats + i, red[i]);
  }
}

// ------------------------------------------------------------ K3b: BN apply
__global__ __launch_bounds__(256) void bn_apply_kernel(
    float* __restrict__ outp, const float* __restrict__ stats,
    const float* __restrict__ gs, const float* __restrict__ bsv,
    const float* __restrict__ gv)
{
  __shared__ float A[16], B[16], AV[8];
  const int tid = threadIdx.x;
  if (tid < 16) {
    const float s = stats[tid], q = stats[16 + tid];
    const float mu = s * (1.f / 20000.f);
    const float var = q * (1.f / 20000.f) - mu * mu;
    const float a = rsqrtf(var + 1e-5f) * gs[tid];
    A[tid] = a;
    B[tid] = bsv[tid] - mu * a;
  } else if (tid < 24) {
    const int u = tid - 16;
    const float vn = stats[32 + u] * (1.f / (20000.f * 3.f));
    AV[u] = rsqrtf(vn + 1e-5f) * gv[u];
  }
  __syncthreads();
  const int nn = blockIdx.x * 256 + tid;
  if (nn < N_NODES_C) {
    float* op = outp + (size_t)nn * D_C;
    float v[40];
#pragma unroll
    for (int i = 0; i < 10; ++i) {
      const float4 t = ld4(op + i * 4);
      v[i * 4] = t.x; v[i * 4 + 1] = t.y; v[i * 4 + 2] = t.z; v[i * 4 + 3] = t.w;
    }
#pragma unroll
    for (int c = 0; c < 16; ++c) v[c] = v[c] * A[c] + B[c];
#pragma unroll
    for (int u = 0; u < 8; ++u) {
      const float a = AV[u];
      v[16 + u * 3] *= a; v[16 + u * 3 + 1] *= a; v[16 + u * 3 + 2] *= a;
    }
#pragma unroll
    for (int i = 0; i < 10; ++i)
      st4(op + i * 4, v[i * 4], v[i * 4 + 1], v[i * 4 + 2], v[i * 4 + 3]);
  }
}

// ---------------------------------------------------------------- launcher
extern "C" void kernel_launch(void* const* d_in, const int* in_sizes, int n_in,
                              void* d_out, int out_size, void* d_ws, size_t ws_size,
                              hipStream_t stream) {
  const float* node_attr = (const float*)d_in[0];
  const float* edge_attr = (const float*)d_in[1];
  const float* edge_sh   = (const float*)d_in[2];
  const float* fc1_w     = (const float*)d_in[3];
  const float* fc1_b     = (const float*)d_in[4];
  const float* fc2_w     = (const float*)d_in[5];
  const float* fc2_b     = (const float*)d_in[6];
  const float* gs        = (const float*)d_in[7];
  const float* bs        = (const float*)d_in[8];
  const float* gv        = (const float*)d_in[9];
  const int*   ei        = (const int*)d_in[10];
  float* out = (float*)d_out;

  char* ws = (char*)d_ws;
  uint32_t* h2   = (uint32_t*)(ws);                      // 320000*64*4 = 81,920,000
  float*    agg  = (float*)(ws + 81920000);              // 20000*40*4  =  3,200,000
  float*    stats= (float*)(ws + 81920000 + 3200000);    // 40*4
  uint32_t* bpk  = (uint32_t*)d_out;                     // 245,760 B scratch

  hipMemsetAsync(agg, 0, 3200000 + 160, stream);
  pack_kernel<<<240, 256, 0, stream>>>(fc2_w, fc1_w, bpk);
  fc1_mfma_kernel<<<1250, 256, 0, stream>>>(edge_attr, bpk, fc1_b, h2);
  edge_mfma_kernel<<<1250, 256, 0, stream>>>(h2, bpk, fc2_b, node_attr, edge_sh, ei, agg);
  resid_stats_kernel<<<79, 256, 0, stream>>>(agg, node_attr, out, stats);
  bn_apply_kernel<<<79, 256, 0, stream>>>(out, stats, gs, bs, gv);
}